// Round 5
// baseline (586.615 us; speedup 1.0000x reference)
//
#include <hip/hip_runtime.h>

using u32 = unsigned int;
using u16 = unsigned short;

typedef __attribute__((ext_vector_type(8))) short bfrag;   // 8 bf16 = 4 VGPR
typedef __attribute__((ext_vector_type(4))) float f32x4;   // MFMA acc

// ---------------- problem constants ----------------
constexpr int T_ = 100, B_ = 2048;
constexpr size_t X_HAT_SZ = (size_t)B_ * T_ * 64;   // 13,107,200 floats

// ---------------- ws layout ----------------
// f0 (enc L0 forward output) bf16 [T][B/16][16][128] at byte 0 (52,428,800 B)
// then packed weights (u16 idx base PKB), then small fp32 tables.
constexpr size_t PKB    = 26214400;        // u16 index of packed-weight base
constexpr size_t PK_A0  = PKB + 0;         // e0 fwd Wih  KT=2
constexpr size_t PK_A1  = PKB + 32768;     // e0 bwd Wih  KT=2
constexpr size_t PK_A2  = PKB + 65536;     // e0 fwd Whh  KT=4
constexpr size_t PK_A3  = PKB + 131072;    // e0 bwd Whh  KT=4
constexpr size_t PK_A4  = PKB + 196608;    // e1 fwd Wih  KT=8
constexpr size_t PK_A5  = PKB + 327680;    // e1 bwd Wih  KT=8
constexpr size_t PK_A6  = PKB + 458752;    // e1 fwd Whh  KT=4
constexpr size_t PK_A7  = PKB + 524288;    // d0 Wih      KT=2
constexpr size_t PK_A8  = PKB + 557056;    // d0 Whh      KT=4
constexpr size_t PK_A9  = PKB + 622592;    // d1 Wih      KT=4
constexpr size_t PK_A10 = PKB + 688128;    // d1 Whh      KT=4
constexpr size_t PK_A11 = PKB + 753664;    // fc_out      KT=4 NF=4  (contiguous after A10)
constexpr size_t PK_ENDU = PKB + 761856;
constexpr size_t O_FCZT  = PK_ENDU * 2;            // fp32 [256][32]
constexpr size_t O_FCIT  = O_FCZT + 32768;         // fp32 [32][256]
constexpr size_t O_FINIT = O_FCIT + 32768;         // fp32 [2048][256]

// ---------------- helpers ----------------
__device__ __forceinline__ u16 f2bfu(float f) {
  u32 u = __float_as_uint(f);
  u += 0x7fffu + ((u >> 16) & 1u);
  return (u16)(u >> 16);
}
__device__ __forceinline__ float bf2f(u32 s) { return __uint_as_float(s << 16); }

__device__ __forceinline__ float sigf(float v) {
  return __builtin_amdgcn_rcpf(1.f + __expf(-v));
}
__device__ __forceinline__ float tanhfast(float v) {
  float a = fabsf(v);
  float e = __expf(-2.f * a);
  float t = fmaf(-2.f * e, __builtin_amdgcn_rcpf(1.f + e), 1.f);
  return v < 0.f ? -t : t;
}

// Opaque pin: forbids rematerialization/sinking of persisted fragments.
template <int N>
__device__ __forceinline__ void pinW(bfrag* W) {
#pragma unroll
  for (int i = 0; i < N; ++i) asm volatile("" : "+v"(W[i]));
}

// A-fragment from padded bf16 LDS tile
__device__ __forceinline__ bfrag ldA(const u16* buf, int strideHalf, int kt, int lane) {
  return *(const bfrag*)(buf + (lane & 15) * strideHalf + kt * 32 + (lane >> 4) * 8);
}

// streaming mm (B-frags from global) — one-shot enc tail only
template <int NKT>
__device__ __forceinline__ void mm(f32x4 acc[4], const bfrag* A, const u16* WP, int w, int lane) {
#pragma unroll
  for (int kt = 0; kt < NKT; ++kt) {
#pragma unroll
    for (int g = 0; g < 4; ++g) {
      bfrag bw = *(const bfrag*)(WP + (((size_t)(kt * 32 + g * 8 + w)) * 64 + lane) * 8);
      acc[g] = __builtin_amdgcn_mfma_f32_16x16x32_bf16(A[kt], bw, acc[g], 0, 0, 0);
    }
  }
}

// persisted-weight load into registers: W[kt*4+g]
template <int NKT>
__device__ __forceinline__ void loadW(bfrag* W, const u16* wsu, size_t base, int w, int lane) {
#pragma unroll
  for (int kt = 0; kt < NKT; ++kt)
#pragma unroll
    for (int g = 0; g < 4; ++g)
      W[kt * 4 + g] = *(const bfrag*)(wsu + base + (((size_t)(kt * 32 + g * 8 + w)) * 64 + lane) * 8);
}

// mm with persisted (register) B-frags
template <int NKT>
__device__ __forceinline__ void mmR(f32x4 acc[4], const u16* lds, int sh, const bfrag* W, int lane) {
#pragma unroll
  for (int kt = 0; kt < NKT; ++kt) {
    bfrag a = ldA(lds, sh, kt, lane);
#pragma unroll
    for (int g = 0; g < 4; ++g)
      acc[g] = __builtin_amdgcn_mfma_f32_16x16x32_bf16(a, W[kt * 4 + g], acc[g], 0, 0, 0);
  }
}

// mm with LDS-resident B-frags (same packed layout, frag_id*1024B + lane*16B)
template <int NKT>
__device__ __forceinline__ void mmL(f32x4 acc[4], const u16* alds, int sh,
                                    const u16* wlds, int w, int lane) {
#pragma unroll
  for (int kt = 0; kt < NKT; ++kt) {
    bfrag a = ldA(alds, sh, kt, lane);
#pragma unroll
    for (int g = 0; g < 4; ++g) {
      bfrag b = *(const bfrag*)(wlds + ((size_t)(kt * 32 + g * 8 + w) * 64 + lane) * 8);
      acc[g] = __builtin_amdgcn_mfma_f32_16x16x32_bf16(a, b, acc[g], 0, 0, 0);
    }
  }
}

// LSTM nonlinearity: lane owns (4 rows, 1 unit); acc = {i,f,g,o}
__device__ __forceinline__ void cellfin(const f32x4 acc[4], float c[4], u16 hq[4]) {
#pragma unroll
  for (int q = 0; q < 4; ++q) {
    float iv = sigf(acc[0][q]);
    float fv = sigf(acc[1][q]);
    float gv = tanhfast(acc[2][q]);
    float ov = sigf(acc[3][q]);
    c[q] = fmaf(fv, c[q], iv * gv);
    hq[q] = f2bfu(ov * tanhfast(c[q]));
  }
}

// ---------------- pack kernel ----------------
__global__ void pack_kernel(const float* e0wih, const float* e0whh,
                            const float* e1wih, const float* e1whh,
                            const float* d0wih, const float* d0whh,
                            const float* d1wih, const float* d1whh,
                            const float* fczw, const float* fciw, const float* fcow,
                            char* ws) {
  int idx = blockIdx.x * 256 + threadIdx.x;
  u16* wsu = (u16*)ws;

  const float* srcs[12] = { e0wih, e0wih + 512 * 64, e0whh, e0whh + 512 * 128,
                            e1wih, e1wih + 512 * 256, e1whh,
                            d0wih, d0whh, d1wih, d1whh, fcow };
  const int Ks[12]  = { 64, 64, 128, 128, 256, 256, 128, 64, 128, 128, 128, 128 };
  const int NFs[12] = { 32, 32, 32, 32, 32, 32, 32, 32, 32, 32, 32, 4 };
  const int cnt[12] = { 32768, 32768, 65536, 65536, 131072, 131072, 65536,
                        32768, 65536, 65536, 65536, 8192 };
  const size_t dst[12] = { PK_A0, PK_A1, PK_A2, PK_A3, PK_A4, PK_A5, PK_A6,
                           PK_A7, PK_A8, PK_A9, PK_A10, PK_A11 };
#pragma unroll
  for (int p = 0; p < 12; ++p) {
    if (idx < cnt[p]) {
      int NF = NFs[p], K = Ks[p];
      int kt = idx / (NF * 512);
      int rem = idx - kt * NF * 512;
      int nf = rem >> 9;
      int li = rem & 511;
      int lane = li >> 3, j = li & 7;
      int n = nf * 16 + (lane & 15);
      int k = kt * 32 + (lane >> 4) * 8 + j;
      wsu[dst[p] + idx] = f2bfu(srcs[p][(size_t)n * K + k]);
      return;
    }
    idx -= cnt[p];
  }
  if (idx < 8192) {  // fczT [256][32] <- fc_z_W (32,256)
    int k = idx >> 5, l = idx & 31;
    ((float*)(ws + O_FCZT))[idx] = fczw[(size_t)l * 256 + k];
    return;
  }
  idx -= 8192;
  if (idx < 8192) {  // fciT [32][256] <- fc_init_W (256,32)
    int l = idx >> 8, o = idx & 255;
    ((float*)(ws + O_FCIT))[idx] = fciw[(size_t)o * 32 + l];
    return;
  }
}
constexpr int PACK_TOTAL = 761856 + 16384;
constexpr int PACK_GRID = (PACK_TOTAL + 255) / 256;

// ---------------- enc L0: bwd (blocks 0-127) and fwd (blocks 128-255), concurrent ----------------
__global__ __attribute__((amdgpu_flat_work_group_size(512, 512), amdgpu_waves_per_eu(1, 2)))
void enc01_kernel(
    const float* __restrict__ x, const float* __restrict__ e0b,
    char* __restrict__ ws, float* __restrict__ out) {
  __shared__ __align__(16) u16 xb[16 * 72];
  __shared__ __align__(16) u16 hA[16 * 136];

  const int tid = threadIdx.x;
  const int lane = tid & 63, w = tid >> 6;
  const int mode = blockIdx.x >> 7;          // 0 = backward, 1 = forward
  const int chunk = blockIdx.x & 127;
  const int b0r = chunk * 16;
  const u16* wsu = (const u16*)ws;
  const int uu = 16 * w + (lane & 15);
  const int rg = lane >> 4;
  const bool rev = (mode == 0);
  u16* dst = rev ? (u16*)out : (u16*)ws;     // b0 -> out-scratch ; f0 -> ws

  bfrag Wi[8], Wh[16];
  loadW<2>(Wi, wsu, rev ? PK_A1 : PK_A0, w, lane);
  loadW<4>(Wh, wsu, rev ? PK_A3 : PK_A2, w, lane);
  pinW<8>(Wi);
  pinW<16>(Wh);
  const float* bias = e0b + (rev ? 512 : 0);
  const float bi = bias[uu], bf = bias[128 + uu], bg = bias[256 + uu], bo = bias[384 + uu];

  const int xr = tid >> 5, xcp = (tid & 31) * 2;
  auto ldx = [&](int t) {
    return *(const float2*)(x + ((size_t)(b0r + xr) * T_ + t) * 64 + xcp);
  };

  for (int i = tid; i < 16 * 136; i += 512) hA[i] = 0;
  float c[4] = {0.f, 0.f, 0.f, 0.f};
  float2 pf = ldx(rev ? T_ - 1 : 0);
  *(u32*)&xb[xr * 72 + xcp] = ((u32)f2bfu(pf.y) << 16) | f2bfu(pf.x);
  __syncthreads();
  pf = ldx(rev ? T_ - 2 : 1);

  for (int s = 0; s < T_; ++s) {
    int t = rev ? T_ - 1 - s : s;
    f32x4 acc[4] = { {bi,bi,bi,bi}, {bf,bf,bf,bf}, {bg,bg,bg,bg}, {bo,bo,bo,bo} };
    mmR<2>(acc, xb, 72, Wi, lane);
    mmR<4>(acc, hA, 136, Wh, lane);
    u16 hq[4];
    cellfin(acc, c, hq);
    __syncthreads();  // B1: all reads of xb/hA done
#pragma unroll
    for (int q = 0; q < 4; ++q) {
      int row = rg * 4 + q;
      hA[row * 136 + uu] = hq[q];
      dst[(((size_t)chunk * T_ + t) * 16 + row) * 128 + uu] = hq[q];
    }
    if (s < T_ - 1)
      *(u32*)&xb[xr * 72 + xcp] = ((u32)f2bfu(pf.y) << 16) | f2bfu(pf.x);
    if (s < T_ - 2) pf = ldx(rev ? t - 2 : t + 2);
    __syncthreads();  // B2
  }
}

// ---------------- enc L1 fwd + tail (128 WGs) ----------------
// A4 (Wih, 32 frags) persisted in VGPRs; A6 (Whh) resident in LDS.
constexpr int E2_A6   = 0;                 // 131072 B
constexpr int E2_CAT  = 131072;            // 16*264*2 = 8448
constexpr int E2_HB   = 139520;            // 16*136*2 = 4352  -> 143872 total
constexpr int E2_LAST = 0;                 // alias over A6 after the loop (16 KB)
constexpr int E2_ZB   = 16384;             // zbuf (2 KB)

__global__ __attribute__((amdgpu_flat_work_group_size(512, 512), amdgpu_waves_per_eu(1, 2)))
void enc2_kernel(
    const float* __restrict__ e1b, const float* __restrict__ fczb,
    const float* __restrict__ lng, const float* __restrict__ lnb,
    const float* __restrict__ fcib,
    char* __restrict__ ws, float* __restrict__ out) {
  __shared__ __align__(16) char sm[143872];
  u16* A6L = (u16*)(sm + E2_A6);
  u16* cat = (u16*)(sm + E2_CAT);
  u16* hB  = (u16*)(sm + E2_HB);

  const int tid = threadIdx.x;
  const int lane = tid & 63, w = tid >> 6;
  const int chunk = blockIdx.x;
  const int b0r = chunk * 16;
  const u16* wsu = (const u16*)ws;
  const int uu = 16 * w + (lane & 15);
  const int rg = lane >> 4;

  {  // copy A6 -> LDS (131072 B = 8192 uint4)
    const uint4* src = (const uint4*)(wsu + PK_A6);
    uint4* d = (uint4*)A6L;
    for (int i = tid; i < 8192; i += 512) d[i] = src[i];
  }
  bfrag W4[32];
  loadW<8>(W4, wsu, PK_A4, w, lane);
  pinW<32>(W4);
  const float bi = e1b[uu], bf = e1b[128 + uu], bg = e1b[256 + uu], bo = e1b[384 + uu];
  for (int i = tid; i < 16 * 136; i += 512) hB[i] = 0;
  float c[4] = {0.f, 0.f, 0.f, 0.f};

  const u32* f0u = (const u32*)ws;    // f0 from enc01 fwd
  const u32* b0u = (const u32*)out;   // b0 from enc01 bwd
  const int prow = tid >> 6, pc4 = tid & 63;
  auto ldrow = [&](const u32* src, int t, int r) {
    return src[(((size_t)chunk * T_ + t) * 16 + r) * 64 + pc4];
  };
  u32 pa = ldrow(f0u, 0, prow), pb = ldrow(f0u, 0, prow + 8);
  u32 pc = ldrow(b0u, 0, prow), pd = ldrow(b0u, 0, prow + 8);
  *(u32*)&cat[prow * 264 + pc4 * 2] = pa;
  *(u32*)&cat[(prow + 8) * 264 + pc4 * 2] = pb;
  *(u32*)&cat[prow * 264 + 128 + pc4 * 2] = pc;
  *(u32*)&cat[(prow + 8) * 264 + 128 + pc4 * 2] = pd;
  __syncthreads();
  pa = ldrow(f0u, 1, prow); pb = ldrow(f0u, 1, prow + 8);
  pc = ldrow(b0u, 1, prow); pd = ldrow(b0u, 1, prow + 8);

  for (int t = 0; t < T_; ++t) {
    f32x4 acc[4] = { {bi,bi,bi,bi}, {bf,bf,bf,bf}, {bg,bg,bg,bg}, {bo,bo,bo,bo} };
    mmR<8>(acc, cat, 264, W4, lane);
    mmL<4>(acc, hB, 136, A6L, w, lane);
    u16 hq[4];
    cellfin(acc, c, hq);
    __syncthreads();  // B1
#pragma unroll
    for (int q = 0; q < 4; ++q) hB[(rg * 4 + q) * 136 + uu] = hq[q];
    if (t < T_ - 1) {
      *(u32*)&cat[prow * 264 + pc4 * 2] = pa;
      *(u32*)&cat[(prow + 8) * 264 + pc4 * 2] = pb;
      *(u32*)&cat[prow * 264 + 128 + pc4 * 2] = pc;
      *(u32*)&cat[(prow + 8) * 264 + 128 + pc4 * 2] = pd;
    }
    if (t < T_ - 2) {
      pa = ldrow(f0u, t + 2, prow); pb = ldrow(f0u, t + 2, prow + 8);
      pc = ldrow(b0u, t + 2, prow); pd = ldrow(b0u, t + 2, prow + 8);
    }
    __syncthreads();  // B2
  }

  // ===== L1 backward: single step from zero state on h0cat[99] (cat holds t=99) =====
  float* lastout = (float*)(sm + E2_LAST);   // clobbers A6L (done with it)
  float* zbuf = (float*)(sm + E2_ZB);
  {
    const float* b = e1b + 512;
    float bi2 = b[uu], bf2 = b[128 + uu], bg2 = b[256 + uu], bo2 = b[384 + uu];
    bfrag a8[8];
#pragma unroll
    for (int kt = 0; kt < 8; ++kt) a8[kt] = ldA(cat, 264, kt, lane);
    f32x4 acc[4] = { {bi2,bi2,bi2,bi2}, {bf2,bf2,bf2,bf2}, {bg2,bg2,bg2,bg2}, {bo2,bo2,bo2,bo2} };
    mm<8>(acc, a8, wsu + PK_A5, w, lane);
#pragma unroll
    for (int q = 0; q < 4; ++q) {
      float iv = sigf(acc[0][q]);
      float gv = tanhfast(acc[2][q]);
      float ov = sigf(acc[3][q]);
      float cv = iv * gv;                       // c_prev = 0
      lastout[(rg * 4 + q) * 256 + 128 + uu] = ov * tanhfast(cv);
    }
    for (int i = tid; i < 2048; i += 512) {
      int r = i >> 7, cc = i & 127;
      lastout[r * 256 + cc] = bf2f(hB[r * 136 + cc]);
    }
    __syncthreads();
  }

  // ===== fc_z + LayerNorm -> z =====
  {
    int r = tid >> 5, l = tid & 31;
    const float* fczT = (const float*)(ws + O_FCZT);
    float acc = fczb[l];
    for (int k = 0; k < 256; ++k) acc = fmaf(lastout[r * 256 + k], fczT[k * 32 + l], acc);
    float s1 = acc, s2 = acc * acc;
#pragma unroll
    for (int off = 16; off >= 1; off >>= 1) {
      s1 += __shfl_xor(s1, off, 32);
      s2 += __shfl_xor(s2, off, 32);
    }
    float mu = s1 * (1.f / 32.f);
    float var = s2 * (1.f / 32.f) - mu * mu;
    float zv = (acc - mu) * rsqrtf(var + 1e-5f) * lng[l] + lnb[l];
    zbuf[r * 32 + l] = zv;
    out[X_HAT_SZ + (size_t)(b0r + r) * 32 + l] = zv;
  }
  __syncthreads();

  // ===== fc_init -> finit (ws) =====
  {
    const float* fciT = (const float*)(ws + O_FCIT);
    float* finit = (float*)(ws + O_FINIT);
    int o = tid & 255, half = tid >> 8;
#pragma unroll
    for (int rr = 0; rr < 8; ++rr) {
      int r = half * 8 + rr;
      float acc = fcib[o];
#pragma unroll
      for (int l = 0; l < 32; ++l) acc = fmaf(zbuf[r * 32 + l], fciT[l * 256 + o], acc);
      finit[(size_t)(b0r + r) * 256 + o] = acc;
    }
  }
}

// ---------------- decoder ----------------
// A7,A8,A9 persisted in VGPRs (40 frags = 160); A10,A11 resident in LDS (144 KB).
constexpr int DC_A10 = 0;           // 131072
constexpr int DC_A11 = 131072;      // 16384
constexpr int DC_XB  = 147456;      // 16*72*2 = 2304
constexpr int DC_HA  = 149760;      // 4352
constexpr int DC_HB  = 154112;      // 4352 -> 158464 total
__global__ __attribute__((amdgpu_flat_work_group_size(512, 512), amdgpu_waves_per_eu(1, 2)))
void dec_kernel(
    const float* __restrict__ d0b, const float* __restrict__ d1b,
    const float* __restrict__ fcob,
    char* __restrict__ ws, float* __restrict__ out) {
  __shared__ __align__(16) char sm[158464];
  u16* A10L = (u16*)(sm + DC_A10);
  u16* A11L = (u16*)(sm + DC_A11);
  u16* xb   = (u16*)(sm + DC_XB);
  u16* hA   = (u16*)(sm + DC_HA);
  u16* hB   = (u16*)(sm + DC_HB);

  const int tid = threadIdx.x;
  const int lane = tid & 63, w = tid >> 6;
  const int chunk = blockIdx.x;
  const int b0r = chunk * 16;
  const u16* wsu = (const u16*)ws;
  const float* finit = (const float*)(ws + O_FINIT);
  const int uu = 16 * w + (lane & 15);
  const int rg = lane >> 4;

  {  // copy A10+A11 (contiguous, 147456 B = 9216 uint4) -> LDS
    const uint4* src = (const uint4*)(wsu + PK_A10);
    uint4* d = (uint4*)A10L;
    for (int i = tid; i < 9216; i += 512) d[i] = src[i];
  }
  bfrag W7[8], W8[16], W9[16];
  loadW<2>(W7, wsu, PK_A7, w, lane);
  loadW<4>(W8, wsu, PK_A8, w, lane);
  loadW<4>(W9, wsu, PK_A9, w, lane);
  pinW<8>(W7);
  pinW<16>(W8);
  pinW<16>(W9);

  for (int i = tid; i < 16 * 72; i += 512) xb[i] = 0;
  for (int i = tid; i < 2048; i += 512) {
    int r = i >> 7, j = i & 127;
    int b = b0r + r;
    hA[r * 136 + j] = f2bfu(finit[(size_t)(b >> 1) * 256 + (b & 1) * 128 + j]);
    hB[r * 136 + j] = f2bfu(finit[(size_t)(1024 + (b >> 1)) * 256 + (b & 1) * 128 + j]);
  }
  const float d0i = d0b[uu], d0f = d0b[128 + uu], d0g = d0b[256 + uu], d0o = d0b[384 + uu];
  const float d1i = d1b[uu], d1f = d1b[128 + uu], d1g = d1b[256 + uu], d1o = d1b[384 + uu];
  const float fob = (w < 4) ? fcob[16 * w + (lane & 15)] : 0.f;
  float c0[4] = {0.f, 0.f, 0.f, 0.f}, c1[4] = {0.f, 0.f, 0.f, 0.f};
  __syncthreads();

  for (int t = 0; t < T_; ++t) {
    // ---- L0 ----
    f32x4 acc[4] = { {d0i,d0i,d0i,d0i}, {d0f,d0f,d0f,d0f}, {d0g,d0g,d0g,d0g}, {d0o,d0o,d0o,d0o} };
    mmR<2>(acc, xb, 72, W7, lane);
    mmR<4>(acc, hA, 136, W8, lane);
    u16 hq[4];
    cellfin(acc, c0, hq);
    __syncthreads();  // B1
#pragma unroll
    for (int q = 0; q < 4; ++q) hA[(rg * 4 + q) * 136 + uu] = hq[q];
    __syncthreads();  // B2
    // ---- L1 ----
    f32x4 acc1[4] = { {d1i,d1i,d1i,d1i}, {d1f,d1f,d1f,d1f}, {d1g,d1g,d1g,d1g}, {d1o,d1o,d1o,d1o} };
    mmR<4>(acc1, hA, 136, W9, lane);
    mmL<4>(acc1, hB, 136, A10L, w, lane);
    u16 hq1[4];
    cellfin(acc1, c1, hq1);
    __syncthreads();  // B3
#pragma unroll
    for (int q = 0; q < 4; ++q) hB[(rg * 4 + q) * 136 + uu] = hq1[q];
    __syncthreads();  // B4
    // ---- fc_out + feedback (waves 0-3) ----
    if (w < 4) {
      f32x4 accP = {fob, fob, fob, fob};
#pragma unroll
      for (int kt = 0; kt < 4; ++kt) {
        bfrag a = ldA(hB, 136, kt, lane);
        bfrag b = *(const bfrag*)(A11L + ((size_t)(kt * 4 + w) * 64 + lane) * 8);
        accP = __builtin_amdgcn_mfma_f32_16x16x32_bf16(a, b, accP, 0, 0, 0);
      }
      int oc = 16 * w + (lane & 15);
#pragma unroll
      for (int q = 0; q < 4; ++q) {
        int row = rg * 4 + q;
        float p = accP[q];
        out[((size_t)(b0r + row) * T_ + t) * 64 + oc] = p;
        xb[row * 72 + oc] = f2bfu(p);
      }
    }
    __syncthreads();  // B5: xb visible for next step
  }
}

// ---------------- launch ----------------
extern "C" void kernel_launch(void* const* d_in, const int* in_sizes, int n_in,
                              void* d_out, int out_size, void* d_ws, size_t ws_size,
                              hipStream_t stream) {
  const float* x     = (const float*)d_in[0];
  const float* e0wih = (const float*)d_in[1];
  const float* e0whh = (const float*)d_in[2];
  const float* e0b   = (const float*)d_in[3];
  const float* e1wih = (const float*)d_in[4];
  const float* e1whh = (const float*)d_in[5];
  const float* e1b   = (const float*)d_in[6];
  const float* fczw  = (const float*)d_in[7];
  const float* fczb  = (const float*)d_in[8];
  const float* lng   = (const float*)d_in[9];
  const float* lnb   = (const float*)d_in[10];
  const float* fciw  = (const float*)d_in[11];
  const float* fcib  = (const float*)d_in[12];
  const float* d0wih = (const float*)d_in[13];
  const float* d0whh = (const float*)d_in[14];
  const float* d0b   = (const float*)d_in[15];
  const float* d1wih = (const float*)d_in[16];
  const float* d1whh = (const float*)d_in[17];
  const float* d1b   = (const float*)d_in[18];
  const float* fcow  = (const float*)d_in[19];
  const float* fcob  = (const float*)d_in[20];
  char* ws = (char*)d_ws;
  float* out = (float*)d_out;

  pack_kernel<<<PACK_GRID, 256, 0, stream>>>(e0wih, e0whh, e1wih, e1whh,
                                             d0wih, d0whh, d1wih, d1whh,
                                             fczw, fciw, fcow, ws);
  enc01_kernel<<<256, 512, 0, stream>>>(x, e0b, ws, out);
  enc2_kernel<<<128, 512, 0, stream>>>(e1b, fczb, lng, lnb, fcib, ws, out);
  dec_kernel<<<128, 512, 0, stream>>>(d0b, d1b, fcob, ws, out);
}